// Round 6
// baseline (382.958 us; speedup 1.0000x reference)
//
#include <hip/hip_runtime.h>
#include <hip/hip_bf16.h>

// ---------------------------------------------------------------------------
// HeteroGNN forward (round 18):
//   - GEMM: direct-to-register streaming with FORCED 2-set software pipeline.
//     R15's direct version failed (0.87 TB/s) because the compiler kept ZERO
//     prefetch registers (VGPR=48: just-in-time loads, ~1 in flight/wave).
//     Now: two named KSet register blocks (12 loads each, k-step 64),
//     rotated; sched_barrier(0) pins load-issue above the next MFMA block;
//     distinct sets give counted vmcnt(12) waits. 12KB/wave in flight,
//     no LDS, no barriers - waves slip like a copy kernel (6.3 TB/s class).
//     Barrier-staged LDS variants are abandoned: R12/13/14/17 all pinned at
//     1.6-1.9 TB/s regardless of BK/occupancy/buffering (lockstep vmcnt(0)
//     drain is structural).
//   - prep / post_t / post_l unchanged from R16 (rest ~226us invariant).
// ---------------------------------------------------------------------------

#define H 128
#define K_DIM 1280
#define LIG_IN 4
#define CAP_L 24    // max ligand degree (lambda=2.5; observed max ~13)
#define CAP_T 48    // max target degree (lambda=12.5; observed max ~34)

typedef __attribute__((ext_vector_type(8))) short bf16x8;
typedef __attribute__((ext_vector_type(4))) float f32x4;

// ---- fused prep: adjacency build + weight cast ----------------------------
// ligand side stores EDGE ID (post_l derives dst via edge_dst[e]);
// target side stores SRC ID (post_t gathers x_ligand rows).
__global__ void prep(const int* __restrict__ src, const int* __restrict__ dst,
                     int* __restrict__ cur_l, int* __restrict__ cur_t,
                     int* __restrict__ adje, int* __restrict__ adjs, int E, int nb_fill,
                     const float* __restrict__ Wl, const float* __restrict__ Wr,
                     __hip_bfloat16* __restrict__ Wt, int nw)
{
    int b = blockIdx.x;
    if (b < nb_fill) {
        int e = b * blockDim.x + threadIdx.x;
        if (e >= E) return;
        int s = src[e], d = dst[e];
        int p = atomicAdd(&cur_l[s], 1);
        adje[s * CAP_L + p] = e;
        int q = atomicAdd(&cur_t[d], 1);
        adjs[d * CAP_T + q] = s;
    } else {
        int idx = (b - nb_fill) * blockDim.x + threadIdx.x;
        if (idx >= nw) return;
        int nr = idx / K_DIM, k = idx - nr * K_DIM;
        float v = (nr < H) ? Wl[k * H + nr] : Wr[k * H + (nr - H)];
        Wt[idx] = __float2bfloat16(v);
    }
}

// ---- GEMM: [M,1280] f32 @ [1280,256] bf16 -> y_tl | t_lin (f32) -----------
__device__ inline bf16x8 cvt8(float4 u, float4 v)
{
    union { __hip_bfloat16 h[8]; bf16x8 f; } r;
    r.h[0] = __float2bfloat16(u.x); r.h[1] = __float2bfloat16(u.y);
    r.h[2] = __float2bfloat16(u.z); r.h[3] = __float2bfloat16(u.w);
    r.h[4] = __float2bfloat16(v.x); r.h[5] = __float2bfloat16(v.y);
    r.h[6] = __float2bfloat16(v.z); r.h[7] = __float2bfloat16(v.w);
    return r.f;
}

// per-wave pipeline register set: one k-step of 64 (12 x 16B loads)
struct KSet {
    float4 u0a, v0a, u0b, v0b;   // A row0: k..k+31 and k+32..k+63
    float4 u1a, v1a, u1b, v1b;   // A row1
    bf16x8 p0a, p0b, p1a, p1b;   // B col0 / col1, both 32-k halves
};

#define LOADSET(S, kk) do {                               \
    S.u0a = *(const float4*)(a0 + (kk));                  \
    S.v0a = *(const float4*)(a0 + (kk) + 4);              \
    S.u0b = *(const float4*)(a0 + (kk) + 32);             \
    S.v0b = *(const float4*)(a0 + (kk) + 36);             \
    S.u1a = *(const float4*)(a1 + (kk));                  \
    S.v1a = *(const float4*)(a1 + (kk) + 4);              \
    S.u1b = *(const float4*)(a1 + (kk) + 32);             \
    S.v1b = *(const float4*)(a1 + (kk) + 36);             \
    S.p0a = *(const bf16x8*)(b0 + (kk));                  \
    S.p0b = *(const bf16x8*)(b0 + (kk) + 32);             \
    S.p1a = *(const bf16x8*)(b1 + (kk));                  \
    S.p1b = *(const bf16x8*)(b1 + (kk) + 32);             \
} while (0)

#define COMPUTE(S) do {                                                               \
    bf16x8 A0 = cvt8(S.u0a, S.v0a);                                                   \
    bf16x8 A1 = cvt8(S.u1a, S.v1a);                                                   \
    acc[0][0] = __builtin_amdgcn_mfma_f32_16x16x32_bf16(A0, S.p0a, acc[0][0], 0, 0, 0); \
    acc[0][1] = __builtin_amdgcn_mfma_f32_16x16x32_bf16(A0, S.p1a, acc[0][1], 0, 0, 0); \
    acc[1][0] = __builtin_amdgcn_mfma_f32_16x16x32_bf16(A1, S.p0a, acc[1][0], 0, 0, 0); \
    acc[1][1] = __builtin_amdgcn_mfma_f32_16x16x32_bf16(A1, S.p1a, acc[1][1], 0, 0, 0); \
    bf16x8 C0 = cvt8(S.u0b, S.v0b);                                                   \
    bf16x8 C1 = cvt8(S.u1b, S.v1b);                                                   \
    acc[0][0] = __builtin_amdgcn_mfma_f32_16x16x32_bf16(C0, S.p0b, acc[0][0], 0, 0, 0); \
    acc[0][1] = __builtin_amdgcn_mfma_f32_16x16x32_bf16(C0, S.p1b, acc[0][1], 0, 0, 0); \
    acc[1][0] = __builtin_amdgcn_mfma_f32_16x16x32_bf16(C1, S.p0b, acc[1][0], 0, 0, 0); \
    acc[1][1] = __builtin_amdgcn_mfma_f32_16x16x32_bf16(C1, S.p1b, acc[1][1], 0, 0, 0); \
} while (0)

// block = 256 thr (4 waves), BM=32, BN=128 (nb in {0,1}); wave tile 32x32.
// MFMA 16x16x32 bf16 operand layout: lane l supplies row/col = l&15,
// k = (l>>4)*8 .. +7  -> per-lane 8 consecutive k (32B f32 / 16B bf16).
__global__ __launch_bounds__(256)
void gemm_pipe(const float* __restrict__ Xf,          // [M,1280] f32
               const unsigned short* __restrict__ Wt, // [256,1280] bf16 n-major
               float* __restrict__ y_tl, float* __restrict__ t_lin, int M)
{
    const int t = threadIdx.x;
    const int w = t >> 6, lane = t & 63;
    const int m16 = lane & 15, q = lane >> 4;      // q in 0..3
    const int mb = blockIdx.x >> 1, nb = blockIdx.x & 1;
    const int bm = mb * 32;
    const int col0 = nb * 128 + w * 32;            // wave's first output col

    const int r0 = min(bm + m16,      M - 1);
    const int r1 = min(bm + m16 + 16, M - 1);
    const float* a0 = Xf + (size_t)r0 * K_DIM + q * 8;
    const float* a1 = Xf + (size_t)r1 * K_DIM + q * 8;
    const unsigned short* b0 = Wt + (size_t)(col0 + m16)      * K_DIM + q * 8;
    const unsigned short* b1 = Wt + (size_t)(col0 + m16 + 16) * K_DIM + q * 8;

    f32x4 acc[2][2];
#pragma unroll
    for (int i = 0; i < 2; ++i)
#pragma unroll
        for (int j = 0; j < 2; ++j)
            acc[i][j] = (f32x4){0.f, 0.f, 0.f, 0.f};

    KSet s0, s1;
    LOADSET(s0, 0);
    LOADSET(s1, 64);
    __builtin_amdgcn_sched_barrier(0);

#pragma unroll
    for (int kk = 0; kk < K_DIM; kk += 128) {
        COMPUTE(s0);                                  // waits only s0's loads
        if (kk + 128 < K_DIM) LOADSET(s0, kk + 128);  // 12 loads in flight
        __builtin_amdgcn_sched_barrier(0);
        COMPUTE(s1);                                  // waits only s1's loads
        if (kk + 192 < K_DIM) LOADSET(s1, kk + 192);
        __builtin_amdgcn_sched_barrier(0);
    }

    // epilogue: row = bm + i*16 + q*4 + r; col(local) = w*32 + j*16 + m16
    float* __restrict__ Y = nb ? t_lin : y_tl;
#pragma unroll
    for (int i = 0; i < 2; ++i) {
#pragma unroll
        for (int j = 0; j < 2; ++j) {
            int col = w * 32 + j * 16 + m16;
#pragma unroll
            for (int r = 0; r < 4; ++r) {
                int row = bm + i * 16 + q * 4 + r;
                if (row < M) Y[(size_t)row * H + col] = acc[i][j][r];
            }
        }
    }
}

// ---- target post (wave per target): gather agg + linear + relu + dot ------
// st[wid] gets b_ep folded in so post_l's edge write is just sl + st[d].
__global__ void post_t(const int* __restrict__ cur_t, const int* __restrict__ adjs,
                       const float* __restrict__ xl, const float* __restrict__ t_lin,
                       const float* __restrict__ W_lt_l, const float* __restrict__ b_lt_l,
                       const float* __restrict__ W_ep, const float* __restrict__ b_ep,
                       float* __restrict__ st, int NT)
{
    int wid = (blockIdx.x * blockDim.x + threadIdx.x) >> 6;
    int lane = threadIdx.x & 63;
    if (wid >= NT) return;
    int cnt = cur_t[wid];
    float a0 = 0.f, a1 = 0.f, a2 = 0.f, a3 = 0.f;
    for (int j = lane; j < cnt; j += 64) {
        int s = adjs[wid * CAP_T + j];
        float4 v = *(const float4*)(xl + (size_t)s * LIG_IN);
        a0 += v.x; a1 += v.y; a2 += v.z; a3 += v.w;
    }
#pragma unroll
    for (int off = 32; off > 0; off >>= 1) {
        a0 += __shfl_xor(a0, off);
        a1 += __shfl_xor(a1, off);
        a2 += __shfl_xor(a2, off);
        a3 += __shfl_xor(a3, off);
    }
    float inv = 1.0f / fmaxf((float)cnt, 1.0f);
    a0 *= inv; a1 *= inv; a2 *= inv; a3 *= inv;
    float acc = 0.f;
#pragma unroll
    for (int p = 0; p < 2; ++p) {
        int h = lane + p * 64;
        float v = a0 * W_lt_l[h] + a1 * W_lt_l[H + h] + a2 * W_lt_l[2 * H + h] +
                  a3 * W_lt_l[3 * H + h] + b_lt_l[h] + t_lin[(size_t)wid * H + h];
        v = fmaxf(v, 0.f);
        acc += v * W_ep[H + h];
    }
#pragma unroll
    for (int off = 32; off > 0; off >>= 1) acc += __shfl_down(acc, off);
    if (lane == 0) st[wid] = acc + b_ep[0];
}

// ---- ligand post + edge write (wave per ligand) ---------------------------
// adje holds edge ids; lane-parallel prefetch of (e, d=edge_dst[e]); the
// gather loop is shfl + one 512B y_tl row load; after the all-lane reduce,
// lane j<cnt writes out[e_j] = sl + st[d_j].
__global__ void post_l(const int* __restrict__ cur_l, const int* __restrict__ adje,
                       const int* __restrict__ edge_dst,
                       const float* __restrict__ y_tl, const float* __restrict__ xl,
                       const float* __restrict__ W_tl_r, const float* __restrict__ b_tl_l,
                       const float* __restrict__ W_ep, const float* __restrict__ st,
                       float* __restrict__ out, int NL)
{
    int wid = (blockIdx.x * blockDim.x + threadIdx.x) >> 6;
    int lane = threadIdx.x & 63;
    if (wid >= NL) return;
    int cnt = cur_l[wid];
    int e = 0, d = 0;
    if (lane < cnt) {
        e = adje[wid * CAP_L + lane];   // coalesced
        d = edge_dst[e];                // one gather instr for the wave
    }
    float a0 = 0.f, a1 = 0.f;   // h = 2*lane, 2*lane+1
    for (int j = 0; j < cnt; ++j) {
        int dj = __shfl(d, j);
        float2 f = ((const float2*)(y_tl + (size_t)dj * H))[lane];  // 512B row load
        a0 += f.x;
        a1 += f.y;
    }
    float inv = 1.0f / fmaxf((float)cnt, 1.0f);
    float4 x = *(const float4*)(xl + (size_t)wid * LIG_IN);
    float acc = 0.f;
    {
        int h = 2 * lane;
        float v = a0 * inv + b_tl_l[h] +
                  x.x * W_tl_r[h] + x.y * W_tl_r[H + h] +
                  x.z * W_tl_r[2 * H + h] + x.w * W_tl_r[3 * H + h];
        v = fmaxf(v, 0.f);
        acc += v * W_ep[h];
    }
    {
        int h = 2 * lane + 1;
        float v = a1 * inv + b_tl_l[h] +
                  x.x * W_tl_r[h] + x.y * W_tl_r[H + h] +
                  x.z * W_tl_r[2 * H + h] + x.w * W_tl_r[3 * H + h];
        v = fmaxf(v, 0.f);
        acc += v * W_ep[h];
    }
#pragma unroll
    for (int off = 32; off > 0; off >>= 1) acc += __shfl_xor(acc, off);  // all lanes
    if (lane < cnt) out[e] = acc + st[d];
}

// ---------------------------------------------------------------------------
extern "C" void kernel_launch(void* const* d_in, const int* in_sizes, int n_in,
                              void* d_out, int out_size, void* d_ws, size_t ws_size,
                              hipStream_t stream) {
    const float* x_ligand = (const float*)d_in[0];
    const float* x_target = (const float*)d_in[1];
    const int*   edge_src = (const int*)d_in[2];
    const int*   edge_dst = (const int*)d_in[3];
    const float* W_lt_l   = (const float*)d_in[4];
    const float* b_lt_l   = (const float*)d_in[5];
    const float* W_lt_r   = (const float*)d_in[6];
    const float* W_tl_l   = (const float*)d_in[7];
    const float* b_tl_l   = (const float*)d_in[8];
    const float* W_tl_r   = (const float*)d_in[9];
    const float* W_ep     = (const float*)d_in[10];
    const float* b_ep     = (const float*)d_in[11];
    float* out = (float*)d_out;

    const int NL = in_sizes[0] / LIG_IN;   // 100000
    const int NT = in_sizes[1] / K_DIM;    // 20000
    const int E  = in_sizes[2];            // 250000

    // ---- workspace layout (16B-aligned offsets) ----
    char* ws = (char*)d_ws;
    size_t off = 0;
    auto take = [&](size_t bytes) { size_t o = off; off += (bytes + 15) & ~(size_t)15; return o; };
    size_t off_Wt     = take((size_t)2 * H * K_DIM * 2); // 655 KB bf16
    size_t off_y_tl   = take((size_t)NT * H * 4);        // 10.24 MB
    size_t off_t_lin  = take((size_t)NT * H * 4);        // 10.24 MB
    size_t off_adje   = take((size_t)NL * CAP_L * 4);    // 9.6 MB
    size_t off_adjs   = take((size_t)NT * CAP_T * 4);    // 3.84 MB
    size_t off_cur_l  = take((size_t)NL * 4);            // <- memset start
    size_t off_cur_t  = take((size_t)NT * 4);            // <- memset end
    size_t off_st     = take((size_t)NT * 4);
    if (off > ws_size) {
        hipMemsetAsync(d_out, 0, (size_t)out_size * 4, stream);
        return;
    }

    __hip_bfloat16* Wt = (__hip_bfloat16*)(ws + off_Wt);
    float* y_tl  = (float*)(ws + off_y_tl);
    float* t_lin = (float*)(ws + off_t_lin);
    int*   adje  = (int*)(ws + off_adje);
    int*   adjs  = (int*)(ws + off_adjs);
    int*   cur_l = (int*)(ws + off_cur_l);
    int*   cur_t = (int*)(ws + off_cur_t);
    float* st    = (float*)(ws + off_st);

    // zero the cursors (contiguous)
    hipMemsetAsync(cur_l, 0, off_st - off_cur_l, stream);

    // 1. fused adjacency build + weight cast
    int nw = 2 * H * K_DIM;
    int nb_fill = (E + 255) / 256;
    int nb_cast = (nw + 255) / 256;
    prep<<<nb_fill + nb_cast, 256, 0, stream>>>(edge_src, edge_dst, cur_l, cur_t,
                                                adje, adjs, E, nb_fill,
                                                W_tl_l, W_lt_r, Wt, nw);

    // 2. GEMM: direct streaming, forced pipeline; grid 1250 (mb=bid>>1, nb=bid&1)
    gemm_pipe<<<((NT + 31) / 32) * 2, 256, 0, stream>>>(x_target, (const unsigned short*)Wt,
                                                        y_tl, t_lin, NT);

    // 3. target post -> st (+ b_ep folded)
    post_t<<<(NT * 64 + 255) / 256, 256, 0, stream>>>(cur_t, adjs, x_ligand, t_lin,
                                                      W_lt_l, b_lt_l, W_ep, b_ep, st, NT);

    // 4. ligand post + edge write -> out
    post_l<<<(NL * 64 + 255) / 256, 256, 0, stream>>>(cur_l, adje, edge_dst, y_tl, x_ligand,
                                                      W_tl_r, b_tl_l, W_ep, st, out, NL);
}

// Round 7
// 359.315 us; speedup vs baseline: 1.0658x; 1.0658x over previous
//
#include <hip/hip_runtime.h>
#include <hip/hip_bf16.h>

// ---------------------------------------------------------------------------
// HeteroGNN forward (round 19):
//   - GEMM "stage-A-once": BM=16 BN=256, 512 thr (8 waves x 16x32 tile),
//     grid 1250. A panel (16 rows x 5120B = 80KB) staged ONCE per block via
//     80 fully-contiguous 1KB global_load_lds bursts (ideal HBM pattern),
//     ONE __syncthreads total. XOR swizzle slot=(c&~15)|((c^r)&15) on the
//     global source; same on ds_read -> 2-way banks (free). B (655KB,
//     L2-resident) read direct-to-register, depth-2 prefetch, ZERO barriers
//     in the K-loop -> waves slip freely; L2 latency ~200cy covered by
//     4 waves/SIMD. A fetched from HBM exactly once (BN=256: no nb dup).
//     R12-R18 post-mortems: per-chunk vmcnt(0) drains pinned all staged
//     variants at 1.6-1.9 TB/s; register-MLP from cold HBM is compiler-
//     defeated (VGPR tell 48/56). This removes both.
//   - prep / post_t / post_l unchanged (verified R16/R17).
// ---------------------------------------------------------------------------

#define H 128
#define K_DIM 1280
#define LIG_IN 4
#define CAP_L 24    // max ligand degree (lambda=2.5; observed max ~13)
#define CAP_T 48    // max target degree (lambda=12.5; observed max ~34)

typedef __attribute__((ext_vector_type(8))) short bf16x8;
typedef __attribute__((ext_vector_type(4))) float f32x4;

#define AS1(p) ((const __attribute__((address_space(1))) void*)(p))
#define AS3(p) ((__attribute__((address_space(3))) void*)(p))

// ---- fused prep: adjacency build + weight cast ----------------------------
__global__ void prep(const int* __restrict__ src, const int* __restrict__ dst,
                     int* __restrict__ cur_l, int* __restrict__ cur_t,
                     int* __restrict__ adje, int* __restrict__ adjs, int E, int nb_fill,
                     const float* __restrict__ Wl, const float* __restrict__ Wr,
                     __hip_bfloat16* __restrict__ Wt, int nw)
{
    int b = blockIdx.x;
    if (b < nb_fill) {
        int e = b * blockDim.x + threadIdx.x;
        if (e >= E) return;
        int s = src[e], d = dst[e];
        int p = atomicAdd(&cur_l[s], 1);
        adje[s * CAP_L + p] = e;
        int q = atomicAdd(&cur_t[d], 1);
        adjs[d * CAP_T + q] = s;
    } else {
        int idx = (b - nb_fill) * blockDim.x + threadIdx.x;
        if (idx >= nw) return;
        int nr = idx / K_DIM, k = idx - nr * K_DIM;
        float v = (nr < H) ? Wl[k * H + nr] : Wr[k * H + (nr - H)];
        Wt[idx] = __float2bfloat16(v);
    }
}

// ---- GEMM: [M,1280] f32 @ [1280,256] bf16 -> y_tl | t_lin (f32) -----------
__device__ inline bf16x8 cvt8(float4 u, float4 v)
{
    union { __hip_bfloat16 h[8]; bf16x8 f; } r;
    r.h[0] = __float2bfloat16(u.x); r.h[1] = __float2bfloat16(u.y);
    r.h[2] = __float2bfloat16(u.z); r.h[3] = __float2bfloat16(u.w);
    r.h[4] = __float2bfloat16(v.x); r.h[5] = __float2bfloat16(v.y);
    r.h[6] = __float2bfloat16(v.z); r.h[7] = __float2bfloat16(v.w);
    return r.f;
}

// MFMA 16x16x32 bf16: lane l supplies row/col = l&15, k = (l>>4)*8..+7;
// D: col = lane&15, row = (lane>>4)*4 + reg.
__global__ __launch_bounds__(512)
void gemm_stage1(const float* __restrict__ Xf,          // [M,1280] f32
                 const unsigned short* __restrict__ Wt, // [256,1280] bf16 n-major
                 float* __restrict__ y_tl, float* __restrict__ t_lin, int M)
{
    __shared__ float As[16 * K_DIM];   // 80 KB, exactly 2 blocks/CU

    const int t = threadIdx.x;
    const int w = t >> 6, lane = t & 63;
    const int m16 = lane & 15, q = lane >> 4;      // q in 0..3
    const int bm = blockIdx.x * 16;

    // ---- stage A once: 8 waves x 2 rows x 5 x 1KB contiguous bursts ----
#pragma unroll
    for (int rr = 0; rr < 2; ++rr) {
        int r = w * 2 + rr;                         // 0..15
        int row = min(bm + r, M - 1);
        const float* rowp = Xf + (size_t)row * K_DIM;
#pragma unroll
        for (int cc = 0; cc < 5; ++cc) {
            int c = cc * 64 + lane;                 // 16B-chunk index in row
            int cs = (c & ~15) | ((c ^ r) & 15);    // pre-swizzled source
            __builtin_amdgcn_global_load_lds(AS1(rowp + cs * 4),
                AS3((char*)As + (r * 320 + cc * 64) * 16), 16, 0, 0);
        }
    }
    __syncthreads();    // the ONLY barrier

    // ---- B pointers: wave covers cols w*32 .. w*32+31 ----
    const unsigned short* bp0 = Wt + (size_t)(w * 32 + m16)      * K_DIM + q * 8;
    const unsigned short* bp1 = Wt + (size_t)(w * 32 + 16 + m16) * K_DIM + q * 8;

    f32x4 acc0 = (f32x4){0.f, 0.f, 0.f, 0.f};
    f32x4 acc1 = (f32x4){0.f, 0.f, 0.f, 0.f};

    // LDS A fragment for k-step ks (row m16, 8 consecutive f32 -> bf16x8)
    auto ldsA = [&](int ks) -> bf16x8 {
        int c0 = ks * 8 + q * 2;
        int c1 = c0 + 1;
        int s0 = m16 * 320 + ((c0 & ~15) | ((c0 ^ m16) & 15));
        int s1 = m16 * 320 + ((c1 & ~15) | ((c1 ^ m16) & 15));
        float4 u = *(const float4*)((const char*)As + s0 * 16);
        float4 v = *(const float4*)((const char*)As + s1 * 16);
        return cvt8(u, v);
    };

    // depth-2 B prefetch (L2-hot; no barriers anywhere in this loop)
    bf16x8 B0a = *(const bf16x8*)(bp0);
    bf16x8 B0b = *(const bf16x8*)(bp1);
    bf16x8 B1a = *(const bf16x8*)(bp0 + 32);
    bf16x8 B1b = *(const bf16x8*)(bp1 + 32);

#pragma unroll
    for (int ks = 0; ks < 40; ks += 2) {
        bf16x8 a0 = ldsA(ks);
        acc0 = __builtin_amdgcn_mfma_f32_16x16x32_bf16(a0, B0a, acc0, 0, 0, 0);
        acc1 = __builtin_amdgcn_mfma_f32_16x16x32_bf16(a0, B0b, acc1, 0, 0, 0);
        if (ks + 2 < 40) {
            B0a = *(const bf16x8*)(bp0 + (ks + 2) * 32);
            B0b = *(const bf16x8*)(bp1 + (ks + 2) * 32);
        }
        __builtin_amdgcn_sched_barrier(0);
        bf16x8 a1 = ldsA(ks + 1);
        acc0 = __builtin_amdgcn_mfma_f32_16x16x32_bf16(a1, B1a, acc0, 0, 0, 0);
        acc1 = __builtin_amdgcn_mfma_f32_16x16x32_bf16(a1, B1b, acc1, 0, 0, 0);
        if (ks + 3 < 40) {
            B1a = *(const bf16x8*)(bp0 + (ks + 3) * 32);
            B1b = *(const bf16x8*)(bp1 + (ks + 3) * 32);
        }
        __builtin_amdgcn_sched_barrier(0);
    }

    // ---- epilogue: row = bm + q*4 + r; col = cb + j*16 + m16 ----
    float* __restrict__ Y;
    int cb;
    if (w < 4) { Y = y_tl;  cb = w * 32; }
    else       { Y = t_lin; cb = (w - 4) * 32; }
#pragma unroll
    for (int r = 0; r < 4; ++r) {
        int row = bm + q * 4 + r;
        if (row < M) {
            Y[(size_t)row * H + cb + m16]      = acc0[r];
            Y[(size_t)row * H + cb + 16 + m16] = acc1[r];
        }
    }
}

// ---- target post (wave per target): gather agg + linear + relu + dot ------
__global__ void post_t(const int* __restrict__ cur_t, const int* __restrict__ adjs,
                       const float* __restrict__ xl, const float* __restrict__ t_lin,
                       const float* __restrict__ W_lt_l, const float* __restrict__ b_lt_l,
                       const float* __restrict__ W_ep, const float* __restrict__ b_ep,
                       float* __restrict__ st, int NT)
{
    int wid = (blockIdx.x * blockDim.x + threadIdx.x) >> 6;
    int lane = threadIdx.x & 63;
    if (wid >= NT) return;
    int cnt = cur_t[wid];
    float a0 = 0.f, a1 = 0.f, a2 = 0.f, a3 = 0.f;
    for (int j = lane; j < cnt; j += 64) {
        int s = adjs[wid * CAP_T + j];
        float4 v = *(const float4*)(xl + (size_t)s * LIG_IN);
        a0 += v.x; a1 += v.y; a2 += v.z; a3 += v.w;
    }
#pragma unroll
    for (int off = 32; off > 0; off >>= 1) {
        a0 += __shfl_xor(a0, off);
        a1 += __shfl_xor(a1, off);
        a2 += __shfl_xor(a2, off);
        a3 += __shfl_xor(a3, off);
    }
    float inv = 1.0f / fmaxf((float)cnt, 1.0f);
    a0 *= inv; a1 *= inv; a2 *= inv; a3 *= inv;
    float acc = 0.f;
#pragma unroll
    for (int p = 0; p < 2; ++p) {
        int h = lane + p * 64;
        float v = a0 * W_lt_l[h] + a1 * W_lt_l[H + h] + a2 * W_lt_l[2 * H + h] +
                  a3 * W_lt_l[3 * H + h] + b_lt_l[h] + t_lin[(size_t)wid * H + h];
        v = fmaxf(v, 0.f);
        acc += v * W_ep[H + h];
    }
#pragma unroll
    for (int off = 32; off > 0; off >>= 1) acc += __shfl_down(acc, off);
    if (lane == 0) st[wid] = acc + b_ep[0];
}

// ---- ligand post + edge write (wave per ligand) ---------------------------
__global__ void post_l(const int* __restrict__ cur_l, const int* __restrict__ adje,
                       const int* __restrict__ edge_dst,
                       const float* __restrict__ y_tl, const float* __restrict__ xl,
                       const float* __restrict__ W_tl_r, const float* __restrict__ b_tl_l,
                       const float* __restrict__ W_ep, const float* __restrict__ st,
                       float* __restrict__ out, int NL)
{
    int wid = (blockIdx.x * blockDim.x + threadIdx.x) >> 6;
    int lane = threadIdx.x & 63;
    if (wid >= NL) return;
    int cnt = cur_l[wid];
    int e = 0, d = 0;
    if (lane < cnt) {
        e = adje[wid * CAP_L + lane];   // coalesced
        d = edge_dst[e];                // one gather instr for the wave
    }
    float a0 = 0.f, a1 = 0.f;   // h = 2*lane, 2*lane+1
    for (int j = 0; j < cnt; ++j) {
        int dj = __shfl(d, j);
        float2 f = ((const float2*)(y_tl + (size_t)dj * H))[lane];  // 512B row load
        a0 += f.x;
        a1 += f.y;
    }
    float inv = 1.0f / fmaxf((float)cnt, 1.0f);
    float4 x = *(const float4*)(xl + (size_t)wid * LIG_IN);
    float acc = 0.f;
    {
        int h = 2 * lane;
        float v = a0 * inv + b_tl_l[h] +
                  x.x * W_tl_r[h] + x.y * W_tl_r[H + h] +
                  x.z * W_tl_r[2 * H + h] + x.w * W_tl_r[3 * H + h];
        v = fmaxf(v, 0.f);
        acc += v * W_ep[h];
    }
    {
        int h = 2 * lane + 1;
        float v = a1 * inv + b_tl_l[h] +
                  x.x * W_tl_r[h] + x.y * W_tl_r[H + h] +
                  x.z * W_tl_r[2 * H + h] + x.w * W_tl_r[3 * H + h];
        v = fmaxf(v, 0.f);
        acc += v * W_ep[h];
    }
#pragma unroll
    for (int off = 32; off > 0; off >>= 1) acc += __shfl_xor(acc, off);  // all lanes
    if (lane < cnt) out[e] = acc + st[d];
}

// ---------------------------------------------------------------------------
extern "C" void kernel_launch(void* const* d_in, const int* in_sizes, int n_in,
                              void* d_out, int out_size, void* d_ws, size_t ws_size,
                              hipStream_t stream) {
    const float* x_ligand = (const float*)d_in[0];
    const float* x_target = (const float*)d_in[1];
    const int*   edge_src = (const int*)d_in[2];
    const int*   edge_dst = (const int*)d_in[3];
    const float* W_lt_l   = (const float*)d_in[4];
    const float* b_lt_l   = (const float*)d_in[5];
    const float* W_lt_r   = (const float*)d_in[6];
    const float* W_tl_l   = (const float*)d_in[7];
    const float* b_tl_l   = (const float*)d_in[8];
    const float* W_tl_r   = (const float*)d_in[9];
    const float* W_ep     = (const float*)d_in[10];
    const float* b_ep     = (const float*)d_in[11];
    float* out = (float*)d_out;

    const int NL = in_sizes[0] / LIG_IN;   // 100000
    const int NT = in_sizes[1] / K_DIM;    // 20000
    const int E  = in_sizes[2];            // 250000

    // ---- workspace layout (16B-aligned offsets) ----
    char* ws = (char*)d_ws;
    size_t off = 0;
    auto take = [&](size_t bytes) { size_t o = off; off += (bytes + 15) & ~(size_t)15; return o; };
    size_t off_Wt     = take((size_t)2 * H * K_DIM * 2); // 655 KB bf16
    size_t off_y_tl   = take((size_t)NT * H * 4);        // 10.24 MB
    size_t off_t_lin  = take((size_t)NT * H * 4);        // 10.24 MB
    size_t off_adje   = take((size_t)NL * CAP_L * 4);    // 9.6 MB
    size_t off_adjs   = take((size_t)NT * CAP_T * 4);    // 3.84 MB
    size_t off_cur_l  = take((size_t)NL * 4);            // <- memset start
    size_t off_cur_t  = take((size_t)NT * 4);            // <- memset end
    size_t off_st     = take((size_t)NT * 4);
    if (off > ws_size) {
        hipMemsetAsync(d_out, 0, (size_t)out_size * 4, stream);
        return;
    }

    __hip_bfloat16* Wt = (__hip_bfloat16*)(ws + off_Wt);
    float* y_tl  = (float*)(ws + off_y_tl);
    float* t_lin = (float*)(ws + off_t_lin);
    int*   adje  = (int*)(ws + off_adje);
    int*   adjs  = (int*)(ws + off_adjs);
    int*   cur_l = (int*)(ws + off_cur_l);
    int*   cur_t = (int*)(ws + off_cur_t);
    float* st    = (float*)(ws + off_st);

    // zero the cursors (contiguous)
    hipMemsetAsync(cur_l, 0, off_st - off_cur_l, stream);

    // 1. fused adjacency build + weight cast
    int nw = 2 * H * K_DIM;
    int nb_fill = (E + 255) / 256;
    int nb_cast = (nw + 255) / 256;
    prep<<<nb_fill + nb_cast, 256, 0, stream>>>(edge_src, edge_dst, cur_l, cur_t,
                                                adje, adjs, E, nb_fill,
                                                W_tl_l, W_lt_r, Wt, nw);

    // 2. GEMM: stage-A-once, barrier-free K-loop; grid 1250 x 512 thr
    gemm_stage1<<<(NT + 15) / 16, 512, 0, stream>>>(x_target, (const unsigned short*)Wt,
                                                    y_tl, t_lin, NT);

    // 3. target post -> st (+ b_ep folded)
    post_t<<<(NT * 64 + 255) / 256, 256, 0, stream>>>(cur_t, adjs, x_ligand, t_lin,
                                                      W_lt_l, b_lt_l, W_ep, b_ep, st, NT);

    // 4. ligand post + edge write -> out
    post_l<<<(NL * 64 + 255) / 256, 256, 0, stream>>>(cur_l, adje, edge_dst, y_tl, x_ligand,
                                                      W_tl_r, b_tl_l, W_ep, st, out, NL);
}